// Round 8
// baseline (142.724 us; speedup 1.0000x reference)
//
#include <hip/hip_runtime.h>
#include <hip/hip_fp16.h>

#define NB 4
#define NH 12
#define DHD 64
#define LQ 512
#define LK 512
#define DM 768

typedef __attribute__((ext_vector_type(4))) _Float16 f16x4;
typedef __attribute__((ext_vector_type(8))) _Float16 f16x8;
typedef __attribute__((ext_vector_type(4))) float f32x4;

// ---------------------------------------------------------------------------
// Kernel 0 (prep): blocks 0..431 transpose+convert Wq/Wk/Wv -> WT f16
// [mat][n][k]; block 432 computes the 3x64 LN tables (lnK pre-scaled by 8).
// ---------------------------------------------------------------------------
__global__ __launch_bounds__(256) void prep_kernel(
    const float* __restrict__ Wq, const float* __restrict__ Wk,
    const float* __restrict__ Wv,
    const float* __restrict__ dpk, const float* __restrict__ dpv,
    const float* __restrict__ gk, const float* __restrict__ bk,
    const float* __restrict__ gv, const float* __restrict__ bv,
    _Float16* __restrict__ WT, float* __restrict__ lnK, float* __restrict__ lnV)
{
    const int bid = blockIdx.x, t = threadIdx.x;
    if (bid < 432) {
        __shared__ float sT[64][65];
        int mat = bid / 144, tile = bid % 144;
        int k0 = (tile / 12) * 64, n0 = (tile % 12) * 64;
        const float* W = (mat == 0) ? Wq : (mat == 1) ? Wk : Wv;
        #pragma unroll
        for (int p = 0; p < 4; ++p) {
            int idx = t + p * 256;
            int ki = idx >> 4, nj = (idx & 15) * 4;
            float4 wv = *(const float4*)&W[(size_t)(k0 + ki) * DM + n0 + nj];
            sT[ki][nj + 0] = wv.x; sT[ki][nj + 1] = wv.y;
            sT[ki][nj + 2] = wv.z; sT[ki][nj + 3] = wv.w;
        }
        __syncthreads();
        _Float16* dst = WT + (size_t)mat * DM * DM;
        #pragma unroll
        for (int p = 0; p < 4; ++p) {
            int idx = t + p * 256;
            int nr = idx >> 4, kj = (idx & 15) * 4;
            f16x4 hv = { (_Float16)sT[kj + 0][nr], (_Float16)sT[kj + 1][nr],
                         (_Float16)sT[kj + 2][nr], (_Float16)sT[kj + 3][nr] };
            *(f16x4*)&dst[(size_t)(n0 + nr) * DM + k0 + kj] = hv;
        }
    } else if (t < 64) {
        int lane = t;
        for (int r = 0; r < 3; ++r) {
            {
                float x = dpk[r * DHD + lane];
                float s = x;
                #pragma unroll
                for (int o = 1; o < 64; o <<= 1) s += __shfl_xor(s, o);
                float mu = s * (1.0f / 64.0f);
                float d = x - mu;
                float v = d * d;
                #pragma unroll
                for (int o = 1; o < 64; o <<= 1) v += __shfl_xor(v, o);
                lnK[r * DHD + lane] =
                    (d * rsqrtf(v * (1.0f / 64.0f) + 1e-5f) * gk[lane] + bk[lane]) * 8.0f;
            }
            {
                float x = dpv[r * DHD + lane];
                float s = x;
                #pragma unroll
                for (int o = 1; o < 64; o <<= 1) s += __shfl_xor(s, o);
                float mu = s * (1.0f / 64.0f);
                float d = x - mu;
                float v = d * d;
                #pragma unroll
                for (int o = 1; o < 64; o <<= 1) v += __shfl_xor(v, o);
                lnV[r * DHD + lane] =
                    d * rsqrtf(v * (1.0f / 64.0f) + 1e-5f) * gv[lane] + bv[lane];
            }
        }
    }
}

// ---------------------------------------------------------------------------
// Kernel 1: QKV projection, fp16 MFMA — verbatim round-7 passing version.
// Tile 64(M)x128(N), K-step 64, grid 32x18 = 576. A staged fp32->f16 on the
// fly; B pure f16x8 copy from WT. Q scaled 1/8 in epilogue.
// Q,K out [B,H,L,64]; V out [B,H,64,L].
// ---------------------------------------------------------------------------
__global__ __launch_bounds__(256) void qkv_mfma(
    const float* __restrict__ hidden, const float* __restrict__ context,
    const _Float16* __restrict__ WT,
    const float* __restrict__ bq, const float* __restrict__ bk,
    const float* __restrict__ bv,
    _Float16* __restrict__ Qh, _Float16* __restrict__ Kh,
    _Float16* __restrict__ VTh)
{
    __shared__ __align__(16) char smem[27648];
    _Float16 (*sA)[72]  = (_Float16(*)[72])smem;             // 64x72  =  9216 B
    _Float16 (*sB)[72]  = (_Float16(*)[72])(smem + 9216);    // 128x72 = 18432 B
    _Float16 (*sC)[136] = (_Float16(*)[136])smem;            // 64x136 = 17408 B
    _Float16 (*sCV)[72] = (_Float16(*)[72])smem;             // 128x72 = 18432 B

    const int t = threadIdx.x;
    const int w = t >> 6, lane = t & 63, g = lane >> 4, c16 = lane & 15;
    const int mat = blockIdx.y / 6, nt0 = blockIdx.y % 6;
    const int m0 = blockIdx.x * 64, n0 = nt0 * 128, head0 = nt0 * 2;
    const float* X     = (mat == 0) ? hidden : context;
    const _Float16* Wt = WT + (size_t)mat * DM * DM;
    const float* bias  = (mat == 0) ? bq : (mat == 1) ? bk : bv;

    f32x4 acc[4][2];
    #pragma unroll
    for (int mt = 0; mt < 4; ++mt)
        #pragma unroll
        for (int nt = 0; nt < 2; ++nt) acc[mt][nt] = (f32x4){0.f, 0.f, 0.f, 0.f};

    for (int kt = 0; kt < 12; ++kt) {
        __syncthreads();
        // A: 64 rows x 64 k, fp32 -> f16 convert during staging
        #pragma unroll
        for (int p = 0; p < 4; ++p) {
            int idx = t + p * 256;
            int row = idx >> 4, c4 = idx & 15;
            float4 xv = *(const float4*)&X[(size_t)(m0 + row) * DM + kt * 64 + c4 * 4];
            f16x4 hv = { (_Float16)xv.x, (_Float16)xv.y,
                         (_Float16)xv.z, (_Float16)xv.w };
            *(f16x4*)&sA[row][c4 * 4] = hv;
        }
        // B: 128 n-rows x 64 k (already [n][k] f16 in WT)
        #pragma unroll
        for (int p = 0; p < 4; ++p) {
            int idx = t + p * 256;
            int n = idx >> 3, c8 = idx & 7;
            *(f16x8*)&sB[n][c8 * 8] =
                *(const f16x8*)&Wt[(size_t)(n0 + n) * DM + kt * 64 + c8 * 8];
        }
        __syncthreads();
        #pragma unroll
        for (int kh = 0; kh < 2; ++kh) {
            f16x8 af[4], bf[2];
            #pragma unroll
            for (int mt = 0; mt < 4; ++mt)
                af[mt] = *(const f16x8*)&sA[mt * 16 + c16][kh * 32 + 8 * g];
            #pragma unroll
            for (int nt = 0; nt < 2; ++nt)
                bf[nt] = *(const f16x8*)&sB[w * 32 + nt * 16 + c16][kh * 32 + 8 * g];
            #pragma unroll
            for (int mt = 0; mt < 4; ++mt)
                #pragma unroll
                for (int nt = 0; nt < 2; ++nt)
                    acc[mt][nt] = __builtin_amdgcn_mfma_f32_16x16x32_f16(
                        af[mt], bf[nt], acc[mt][nt], 0, 0, 0);
        }
    }

    const float sc = (mat == 0) ? 0.125f : 1.0f;
    float bb[2];
    #pragma unroll
    for (int nt = 0; nt < 2; ++nt)
        bb[nt] = bias[n0 + w * 32 + nt * 16 + c16] * sc;
    __syncthreads();

    const int bbat = m0 >> 9, l0 = m0 & 511;
    if (mat < 2) {
        #pragma unroll
        for (int mt = 0; mt < 4; ++mt)
            #pragma unroll
            for (int nt = 0; nt < 2; ++nt)
                #pragma unroll
                for (int r = 0; r < 4; ++r)
                    sC[mt * 16 + 4 * g + r][w * 32 + nt * 16 + c16] =
                        (_Float16)(acc[mt][nt][r] * sc + bb[nt]);
        __syncthreads();
        _Float16* dst = (mat == 0) ? Qh : Kh;
        #pragma unroll
        for (int p = 0; p < 4; ++p) {
            int idx = t + p * 256;
            int row = idx >> 4, cg = idx & 15;
            int hl = cg >> 3, d8 = cg & 7;
            *(f16x8*)&dst[((size_t)(bbat * NH + head0 + hl) * LQ + l0 + row) * DHD + d8 * 8] =
                *(const f16x8*)&sC[row][cg * 8];
        }
    } else {
        #pragma unroll
        for (int mt = 0; mt < 4; ++mt)
            #pragma unroll
            for (int nt = 0; nt < 2; ++nt)
                #pragma unroll
                for (int r = 0; r < 4; ++r)
                    sCV[w * 32 + nt * 16 + c16][mt * 16 + 4 * g + r] =
                        (_Float16)(acc[mt][nt][r] + bb[nt]);
        __syncthreads();
        #pragma unroll
        for (int p = 0; p < 4; ++p) {
            int idx = t + p * 256;
            int n = idx >> 3, c8 = idx & 7;
            *(f16x8*)&VTh[((size_t)(bbat * NH + head0 + (n >> 6)) * DHD + (n & 63)) * LK
                          + l0 + c8 * 8] = *(const f16x8*)&sCV[n][c8 * 8];
        }
    }
}

// ---------------------------------------------------------------------------
// Kernel 2: attention, fp16 MFMA, q-tile 16 — the round-2 replay-proven
// structure (byte sArc staging, global-load tb, sP[16][520], grid 1536 =
// 6 blocks/CU), adapted only for folded scales: Q carries 1/8, lnK carries
// x8, so scores need no *0.125 and tb is Q.lnK directly.
// ---------------------------------------------------------------------------
__global__ __launch_bounds__(256) void attn_mfma(
    const _Float16* __restrict__ Qh, const _Float16* __restrict__ Kh,
    const _Float16* __restrict__ VTh, const float* __restrict__ maskp,
    const int* __restrict__ garc, const float* __restrict__ lnK,
    const float* __restrict__ lnV, float* __restrict__ outp)
{
    __shared__ __align__(16) _Float16 sP[16][520];   // 16640 B
    __shared__ unsigned char sArc[16][512];          // 8192 B
    __shared__ float sTb[16][4];
    __shared__ float sMax[4][16];
    __shared__ float sStat[4][16][4];
    __shared__ float sFin[16][4];

    const int t = threadIdx.x;
    const int w = t >> 6, lane = t & 63, g = lane >> 4, c16 = lane & 15;
    const int bx = blockIdx.x;
    const int qt = bx & 31, h = (bx >> 5) % NH, b = bx / (32 * NH);
    const int q0 = qt * 16;
    const int kw = w * 128;

    const _Float16* Qb = Qh + ((size_t)(b * NH + h) * LQ) * DHD;
    const _Float16* Kb = Kh + ((size_t)(b * NH + h) * LK) * DHD;
    const _Float16* Vb = VTh + ((size_t)(b * NH + h) * DHD) * LK;

    // stage arc rows (16 x 512 int32 -> u8)
    const int* garcRow = garc + ((size_t)(b * LQ + q0)) * LK;
    unsigned char* sArcFlat = &sArc[0][0];
    #pragma unroll
    for (int p = 0; p < 8; ++p) {
        int idx = t + p * 256;
        int4 a4 = *(const int4*)&garcRow[idx * 4];
        uchar4 u = { (unsigned char)a4.x, (unsigned char)a4.y,
                     (unsigned char)a4.z, (unsigned char)a4.w };
        *(uchar4*)&sArcFlat[idx * 4] = u;
    }
    // tb[q][r] = q . lnK[r]  (192 threads, 4-lane partial sums)
    // Q carries 1/8, lnK pre-scaled x8 -> product is the unscaled dot.
    if (t < 192) {
        int q = t / 12, rem = t % 12, rr = rem >> 2, part = rem & 3;
        float a = 0.f;
        const _Float16* qrow = Qb + (q0 + q) * DHD;
        #pragma unroll
        for (int d0 = 0; d0 < 16; ++d0) {
            int d = part * 16 + d0;
            a += (float)qrow[d] * lnK[rr * 64 + d];
        }
        a += __shfl_xor(a, 1);
        a += __shfl_xor(a, 2);
        if (part == 0) sTb[q][rr] = a;
    }
    // Q A-fragments straight from global (16B per lane)
    f16x8 qa0 = *(const f16x8*)&Qb[(q0 + c16) * DHD + 8 * g];
    f16x8 qa1 = *(const f16x8*)&Qb[(q0 + c16) * DHD + 32 + 8 * g];
    __syncthreads();

    // QK^T + score fixup (arc term, mask); scores stay in regs
    f32x4 c[8];
    int aPack[8];
    float rm[4] = {-1e30f, -1e30f, -1e30f, -1e30f};
    #pragma unroll
    for (int tt = 0; tt < 8; ++tt) {
        int kg = kw + tt * 16 + c16;
        f16x8 kb0 = *(const f16x8*)&Kb[kg * DHD + 8 * g];
        f16x8 kb1 = *(const f16x8*)&Kb[kg * DHD + 32 + 8 * g];
        f32x4 s = (f32x4){0.f, 0.f, 0.f, 0.f};
        s = __builtin_amdgcn_mfma_f32_16x16x32_f16(qa0, kb0, s, 0, 0, 0);
        s = __builtin_amdgcn_mfma_f32_16x16x32_f16(qa1, kb1, s, 0, 0, 0);
        float mv = maskp[b * LK + kg];
        int ap = 0;
        #pragma unroll
        for (int r = 0; r < 4; ++r) {
            int a = sArc[4 * g + r][kg];
            ap |= a << (8 * r);
            float sv = s[r] + sTb[4 * g + r][a] + mv;
            s[r] = sv;
            rm[r] = fmaxf(rm[r], sv);
        }
        c[tt] = s;
        aPack[tt] = ap;
    }

    // row max: shuffle over the 16 key-lanes, then cross-wave via LDS
    #pragma unroll
    for (int r = 0; r < 4; ++r) {
        float m = rm[r];
        m = fmaxf(m, __shfl_xor(m, 1));
        m = fmaxf(m, __shfl_xor(m, 2));
        m = fmaxf(m, __shfl_xor(m, 4));
        m = fmaxf(m, __shfl_xor(m, 8));
        rm[r] = m;
    }
    if (c16 == 0) {
        #pragma unroll
        for (int r = 0; r < 4; ++r) sMax[w][4 * g + r] = rm[r];
    }
    __syncthreads();
    float Mr[4];
    #pragma unroll
    for (int r = 0; r < 4; ++r) {
        int q = 4 * g + r;
        Mr[r] = fmaxf(fmaxf(sMax[0][q], sMax[1][q]), fmaxf(sMax[2][q], sMax[3][q]));
    }

    // exp, row sums + 3 arc-bucket sums (unnormalized), P -> LDS f16
    float rs[4] = {0, 0, 0, 0}, b0s[4] = {0, 0, 0, 0},
          b1s[4] = {0, 0, 0, 0}, b2s[4] = {0, 0, 0, 0};
    #pragma unroll
    for (int tt = 0; tt < 8; ++tt) {
        int kg = kw + tt * 16 + c16;
        #pragma unroll
        for (int r = 0; r < 4; ++r) {
            float e = __expf(c[tt][r] - Mr[r]);
            int a = (aPack[tt] >> (8 * r)) & 255;
            rs[r] += e;
            b0s[r] += (a == 0) ? e : 0.f;
            b1s[r] += (a == 1) ? e : 0.f;
            b2s[r] += (a == 2) ? e : 0.f;
            sP[4 * g + r][kg] = (_Float16)e;
        }
    }
    #pragma unroll
    for (int r = 0; r < 4; ++r) {
        #pragma unroll
        for (int o = 1; o < 16; o <<= 1) {
            rs[r]  += __shfl_xor(rs[r], o);
            b0s[r] += __shfl_xor(b0s[r], o);
            b1s[r] += __shfl_xor(b1s[r], o);
            b2s[r] += __shfl_xor(b2s[r], o);
        }
    }
    if (c16 == 0) {
        #pragma unroll
        for (int r = 0; r < 4; ++r) {
            float4 v = make_float4(rs[r], b0s[r], b1s[r], b2s[r]);
            *(float4*)&sStat[w][4 * g + r][0] = v;
        }
    }
    __syncthreads();   // sP + sStat visible to all waves
    if (t < 16) {
        float4 tot = make_float4(0.f, 0.f, 0.f, 0.f);
        #pragma unroll
        for (int ww = 0; ww < 4; ++ww) {
            float4 v = *(const float4*)&sStat[ww][t][0];
            tot.x += v.x; tot.y += v.y; tot.z += v.z; tot.w += v.w;
        }
        sFin[t][0] = 1.0f / tot.x;
        sFin[t][1] = tot.y; sFin[t][2] = tot.z; sFin[t][3] = tot.w;
    }

    // PV: A from sP (LDS), B from transposed V (global, contiguous 16B)
    f32x4 o = (f32x4){0.f, 0.f, 0.f, 0.f};
    const _Float16* vrow = Vb + (size_t)(w * 16 + c16) * LK;
    #pragma unroll
    for (int ktile = 0; ktile < 16; ++ktile) {
        f16x8 pa = *(const f16x8*)&sP[c16][ktile * 32 + 8 * g];
        f16x8 vb = *(const f16x8*)&vrow[ktile * 32 + 8 * g];
        o = __builtin_amdgcn_mfma_f32_16x16x32_f16(pa, vb, o, 0, 0, 0);
    }
    __syncthreads();   // sFin visible

    // epilogue: rank-3 lnV correction + normalize, store fp32
    int d = w * 16 + c16;
    float lv0 = lnV[d], lv1 = lnV[64 + d], lv2 = lnV[128 + d];
    #pragma unroll
    for (int r = 0; r < 4; ++r) {
        int q = 4 * g + r;
        float4 st = *(const float4*)&sFin[q][0];
        float val = (o[r] + st.y * lv0 + st.z * lv1 + st.w * lv2) * st.x;
        outp[((size_t)(b * LQ + q0 + q)) * DM + h * DHD + d] = val;
    }
}

// ---------------------------------------------------------------------------
extern "C" void kernel_launch(void* const* d_in, const int* in_sizes, int n_in,
                              void* d_out, int out_size, void* d_ws, size_t ws_size,
                              hipStream_t stream) {
    const float* hidden  = (const float*)d_in[0];
    const float* context = (const float*)d_in[1];
    const float* mask    = (const float*)d_in[2];
    const int*   garc    = (const int*)d_in[3];
    const float* Wq = (const float*)d_in[4];
    const float* bq = (const float*)d_in[5];
    const float* Wk = (const float*)d_in[6];
    const float* bk = (const float*)d_in[7];
    const float* Wv = (const float*)d_in[8];
    const float* bv = (const float*)d_in[9];
    const float* dpk  = (const float*)d_in[10];
    const float* dpv  = (const float*)d_in[11];
    const float* lnkg = (const float*)d_in[12];
    const float* lnkb = (const float*)d_in[13];
    const float* lnvg = (const float*)d_in[14];
    const float* lnvb = (const float*)d_in[15];
    float* out = (float*)d_out;

    const size_t perT = (size_t)NB * NH * LQ * DHD;   // 1,572,864 halves
    _Float16* Qh  = (_Float16*)d_ws;
    _Float16* Kh  = Qh + perT;
    _Float16* VTh = Kh + perT;
    _Float16* WT  = VTh + perT;                        // 3*768*768 halves
    float* lnK = (float*)(WT + (size_t)3 * DM * DM);
    float* lnV = lnK + 192;

    prep_kernel<<<433, 256, 0, stream>>>(Wq, Wk, Wv, dpk, dpv,
                                         lnkg, lnkb, lnvg, lnvb, WT, lnK, lnV);
    qkv_mfma<<<dim3(32, 18), 256, 0, stream>>>(hidden, context, WT,
                                               bq, bk, bv, Qh, Kh, VTh);
    attn_mfma<<<1536, 256, 0, stream>>>(Qh, Kh, VTh, mask, garc, lnK, lnV, out);
}